// Round 3
// baseline (855.422 us; speedup 1.0000x reference)
//
#include <hip/hip_runtime.h>
#include <math.h>

#define B_   2
#define S_   3072
#define C_   256
#define NH   8
#define HD   32
#define HALF 16
#define NELEM (B_*S_*C_)   // 1,572,864
#define MLROWS (B_*NH*S_)  // 49,152 rows per split

__device__ __forceinline__ float dot4(float4 a, float4 b) {
    return a.x*b.x + a.y*b.y + a.z*b.z + a.w*b.w;
}

// ---------------- GEMM: out[M x 256] = (A[M x 256] @ W[256 x 256]^T (+bias))*scl ---
// 64x64 tile, 256 threads, 4x4 microtile, K staged in 32-wide chunks.
__device__ __forceinline__ void gemm_nt_body(const float* __restrict__ A,
                                             const float* __restrict__ W,
                                             const float* __restrict__ bias,
                                             float* __restrict__ out,
                                             float scl)
{
    __shared__ float As[64][36];   // +4 pad keeps float4 alignment, breaks some conflicts
    __shared__ float Ws[64][36];
    const int tid  = threadIdx.x;
    const int tx4  = (tid & 15) * 4;   // col group
    const int ty4  = (tid >> 4) * 4;   // row group
    const int row0 = blockIdx.x * 64;
    const int col0 = blockIdx.y * 64;

    float acc[4][4] = {};

    for (int kc = 0; kc < C_; kc += 32) {
        __syncthreads();
        #pragma unroll
        for (int l = tid; l < 512; l += 256) {
            const int r  = l >> 3;
            const int k4 = (l & 7) * 4;
            *(float4*)&As[r][k4] = *(const float4*)&A[(size_t)(row0 + r)*C_ + kc + k4];
            *(float4*)&Ws[r][k4] = *(const float4*)&W[(size_t)(col0 + r)*C_ + kc + k4];
        }
        __syncthreads();
        #pragma unroll
        for (int k4 = 0; k4 < 32; k4 += 4) {
            float4 a0 = *(const float4*)&As[ty4+0][k4];
            float4 a1 = *(const float4*)&As[ty4+1][k4];
            float4 a2 = *(const float4*)&As[ty4+2][k4];
            float4 a3 = *(const float4*)&As[ty4+3][k4];
            float4 w0 = *(const float4*)&Ws[tx4+0][k4];
            float4 w1 = *(const float4*)&Ws[tx4+1][k4];
            float4 w2 = *(const float4*)&Ws[tx4+2][k4];
            float4 w3 = *(const float4*)&Ws[tx4+3][k4];
            acc[0][0] += dot4(a0,w0); acc[0][1] += dot4(a0,w1);
            acc[0][2] += dot4(a0,w2); acc[0][3] += dot4(a0,w3);
            acc[1][0] += dot4(a1,w0); acc[1][1] += dot4(a1,w1);
            acc[1][2] += dot4(a1,w2); acc[1][3] += dot4(a1,w3);
            acc[2][0] += dot4(a2,w0); acc[2][1] += dot4(a2,w1);
            acc[2][2] += dot4(a2,w2); acc[2][3] += dot4(a2,w3);
            acc[3][0] += dot4(a3,w0); acc[3][1] += dot4(a3,w1);
            acc[3][2] += dot4(a3,w2); acc[3][3] += dot4(a3,w3);
        }
    }

    float4 bv = make_float4(0.f, 0.f, 0.f, 0.f);
    if (bias) bv = *(const float4*)&bias[col0 + tx4];
    #pragma unroll
    for (int rr = 0; rr < 4; ++rr) {
        float4 o = make_float4((acc[rr][0] + bv.x)*scl, (acc[rr][1] + bv.y)*scl,
                               (acc[rr][2] + bv.z)*scl, (acc[rr][3] + bv.w)*scl);
        *(float4*)&out[(size_t)(row0 + ty4 + rr)*C_ + col0 + tx4] = o;
    }
}

__global__ __launch_bounds__(256) void qkv_kernel(
        const float* __restrict__ x,
        const float* __restrict__ Wq, const float* __restrict__ Wk, const float* __restrict__ Wv,
        const float* __restrict__ qb, const float* __restrict__ vb,
        float* __restrict__ q, float* __restrict__ k, float* __restrict__ v)
{
    // scale 1/sqrt(32) folded into q projection (RoPE rotation commutes with scalar)
    if      (blockIdx.z == 0) gemm_nt_body(x, Wq, qb,      q, 0.17677669529663687f);
    else if (blockIdx.z == 1) gemm_nt_body(x, Wk, nullptr, k, 1.0f);
    else                      gemm_nt_body(x, Wv, vb,      v, 1.0f);
}

__global__ __launch_bounds__(256) void out_gemm_kernel(
        const float* __restrict__ ctx, const float* __restrict__ Wo,
        const float* __restrict__ bo, float* __restrict__ out)
{
    gemm_nt_body(ctx, Wo, bo, out, 1.0f);
}

// ---------------- RoPE (in place on q and k), phase in double --------------------
__global__ __launch_bounds__(256) void rope_kernel(float* __restrict__ q, float* __restrict__ k)
{
    const int idx = blockIdx.x * 256 + threadIdx.x;   // grid sized exactly
    const int per_tensor = B_ * S_ * NH * HALF;       // 786432
    float* t = (idx < per_tensor) ? q : k;
    const int i   = (idx < per_tensor) ? idx : idx - per_tensor;
    const int j   = i & 15;
    const int hh  = (i >> 4) & 7;
    const int row = i >> 7;                            // 0 .. B_*S_-1
    const int s   = (row >= S_) ? (row - S_) : row;    // position within batch

    const double invf = exp(-log(10000.0) * (double)j * (1.0 / 16.0));
    // match reference: angle formed in fp32, then accurate sin/cos of that angle
    const float  angf = (float)((double)s * invf);
    double sn, cs;
    sincos((double)angf, &sn, &cs);
    const float c = (float)cs, sf = (float)sn;

    const size_t base = (size_t)row * C_ + hh * HD + j;
    const float t1 = t[base];
    const float t2 = t[base + HALF];
    t[base]        = t1 * c - t2 * sf;
    t[base + HALF] = t2 * c + t1 * sf;
}

// ---------------- softmax helpers: tree reductions (short dep chains) -------------
__device__ __forceinline__ float tree_max8(const float s[8]) {
    float t0 = fmaxf(s[0], s[4]), t1 = fmaxf(s[1], s[5]);
    float t2 = fmaxf(s[2], s[6]), t3 = fmaxf(s[3], s[7]);
    return fmaxf(fmaxf(t0, t2), fmaxf(t1, t3));
}
__device__ __forceinline__ float tree_sum8(const float s[8]) {
    float t0 = s[0] + s[4], t1 = s[1] + s[5];
    float t2 = s[2] + s[6], t3 = s[3] + s[7];
    return (t0 + t2) + (t1 + t3);
}

// ---------------- Flash attention, fp32, split-KV --------------------------------
// grid (S_/64, NH, B_*NSPLIT), 128 threads (2 waves). Thread t: rows
// {qb+(t>>2), qb+(t>>2)+32}, col sub-group sub = t&3 handles cols c = sub + 4*i.
// KVBLK=32, LDS 18 KB (double-buffered K+V) -> 8 blocks/CU LDS cap.
// SPLIT: 1536 blocks = 6 resident blocks/CU = 3 waves/SIMD (launch_bounds(128,3)),
// doubling TLP vs the 768-block single-pass version; each block covers half the KV
// range and emits raw acc + (m,l); combine_kernel merges the two halves.
template<bool SPLIT>
__global__ __launch_bounds__(128, 3) void attn_kernel(
        const float* __restrict__ q, const float* __restrict__ k,
        const float* __restrict__ v, float* __restrict__ outp,
        float* __restrict__ pm, float* __restrict__ pl)
{
    __shared__ float Ks[2][32][36];
    __shared__ float Vs[2][32][36];

    const int tid = threadIdx.x;
    const int sub = tid & 3;
    const int rr  = tid >> 2;                 // 0..31
    const int qb  = blockIdx.x * 64;
    const int hh  = blockIdx.y;
    const int split = SPLIT ? (blockIdx.z & 1) : 0;
    const int b     = SPLIT ? (blockIdx.z >> 1) : blockIdx.z;
    const int kt0   = split * (S_/2);
    const int NT    = SPLIT ? (S_/2)/32 : S_/32;   // 48 or 96 tiles

    const size_t rowbase = (size_t)b * S_;
    const int coloff = hh * HD;

    // staging: thread loads rows sr+{0,16}, cols [sk, sk+4) of the 32x32 tile
    const int sr = tid >> 3;                  // 0..15
    const int sk = (tid & 7) * 4;             // 0,4,...,28
    const float* kptr = &k[(rowbase + kt0)*C_ + coloff + sk];
    const float* vptr = &v[(rowbase + kt0)*C_ + coloff + sk];

    const int r0 = qb + rr, r1 = qb + rr + 32;

    float qreg0[32], qreg1[32];               // scale already folded into q
    #pragma unroll
    for (int k4 = 0; k4 < 32; k4 += 4) {
        float4 t0 = *(const float4*)&q[(rowbase + r0)*C_ + coloff + k4];
        float4 t1 = *(const float4*)&q[(rowbase + r1)*C_ + coloff + k4];
        qreg0[k4+0]=t0.x; qreg0[k4+1]=t0.y; qreg0[k4+2]=t0.z; qreg0[k4+3]=t0.w;
        qreg1[k4+0]=t1.x; qreg1[k4+1]=t1.y; qreg1[k4+2]=t1.z; qreg1[k4+3]=t1.w;
    }

    float4 kr0, kr1, vr0, vr1;

#define LOAD_TILE(t_) { \
        const size_t o = (size_t)((t_)*32 + sr) * C_; \
        kr0 = *(const float4*)&kptr[o        ]; \
        kr1 = *(const float4*)&kptr[o + 16*C_]; \
        vr0 = *(const float4*)&vptr[o        ]; \
        vr1 = *(const float4*)&vptr[o + 16*C_]; }

#define WRITE_TILE(bufi) { \
        *(float4*)&Ks[bufi][sr   ][sk] = kr0; \
        *(float4*)&Ks[bufi][sr+16][sk] = kr1; \
        *(float4*)&Vs[bufi][sr   ][sk] = vr0; \
        *(float4*)&Vs[bufi][sr+16][sk] = vr1; }

    float m0 = -1e30f, m1 = -1e30f, l0 = 0.f, l1 = 0.f;
    float acc0[32] = {}, acc1[32] = {};

    // prologue: tile 0 into buf0, tile 1 into regs
    LOAD_TILE(0);
    WRITE_TILE(0);
    LOAD_TILE(1);
    __syncthreads();

    for (int t = 0; t < NT; ++t) {
        const int cur = t & 1;
        const int nxt = cur ^ 1;
        if (t + 1 < NT) {
            WRITE_TILE(nxt);                  // tile t+1 regs -> other buffer
            if (t + 2 < NT) LOAD_TILE(t + 2); // refill regs; hides under compute
        }

        const float (*Kc)[36] = Ks[cur];
        const float (*Vc)[36] = Vs[cur];

        __builtin_amdgcn_s_setprio(1);
        // ---- scores for 8 cols x 2 rows (Ks read shared across both rows)
        float sc0[8], sc1[8];
        #pragma unroll
        for (int i = 0; i < 8; ++i) {
            const int c = sub + 4*i;           // 4 distinct rows/instr -> conflict-free
            float d0 = 0.f, d1 = 0.f;
            #pragma unroll
            for (int k4 = 0; k4 < 32; k4 += 4) {
                float4 kk = *(const float4*)&Kc[c][k4];
                d0 += qreg0[k4+0]*kk.x + qreg0[k4+1]*kk.y + qreg0[k4+2]*kk.z + qreg0[k4+3]*kk.w;
                d1 += qreg1[k4+0]*kk.x + qreg1[k4+1]*kk.y + qreg1[k4+2]*kk.z + qreg1[k4+3]*kk.w;
            }
            sc0[i] = d0; sc1[i] = d1;
        }

        // ---- online softmax bookkeeping, both rows (tree reductions)
        {
            float tm0 = tree_max8(sc0);
            float tm1 = tree_max8(sc1);
            tm0 = fmaxf(tm0, __shfl_xor(tm0, 1));
            tm0 = fmaxf(tm0, __shfl_xor(tm0, 2));
            tm1 = fmaxf(tm1, __shfl_xor(tm1, 1));
            tm1 = fmaxf(tm1, __shfl_xor(tm1, 2));
            const float mnew0 = fmaxf(m0, tm0);
            const float mnew1 = fmaxf(m1, tm1);
            const float f0 = __expf(m0 - mnew0);
            const float f1 = __expf(m1 - mnew1);
            m0 = mnew0; m1 = mnew1; l0 *= f0; l1 *= f1;
            #pragma unroll
            for (int dd = 0; dd < 32; ++dd) { acc0[dd] *= f0; acc1[dd] *= f1; }
            #pragma unroll
            for (int i = 0; i < 8; ++i) {
                sc0[i] = __expf(sc0[i] - mnew0);
                sc1[i] = __expf(sc1[i] - mnew1);
            }
            l0 += tree_sum8(sc0);
            l1 += tree_sum8(sc1);
        }

        // ---- PV, fused over both rows: each Vs float4 read feeds 8 FMAs
        #pragma unroll
        for (int i = 0; i < 8; ++i) {
            const int c = sub + 4*i;
            const float p0 = sc0[i];
            const float p1 = sc1[i];
            #pragma unroll
            for (int d4 = 0; d4 < 8; ++d4) {
                float4 vv = *(const float4*)&Vc[c][d4*4];
                acc0[d4*4+0] += p0*vv.x; acc0[d4*4+1] += p0*vv.y;
                acc0[d4*4+2] += p0*vv.z; acc0[d4*4+3] += p0*vv.w;
                acc1[d4*4+0] += p1*vv.x; acc1[d4*4+1] += p1*vv.y;
                acc1[d4*4+2] += p1*vv.z; acc1[d4*4+3] += p1*vv.w;
            }
        }
        __builtin_amdgcn_s_setprio(0);

        __syncthreads();                       // single barrier per tile
    }

#undef LOAD_TILE
#undef WRITE_TILE

    // ---- reduce across the 4-lane row group; normalize only if single-pass
    l0 += __shfl_xor(l0, 1); l0 += __shfl_xor(l0, 2);
    l1 += __shfl_xor(l1, 1); l1 += __shfl_xor(l1, 2);
    const float inv0 = SPLIT ? 1.f : 1.f / l0;
    const float inv1 = SPLIT ? 1.f : 1.f / l1;
    #pragma unroll
    for (int dd = 0; dd < 32; ++dd) {
        float a = acc0[dd]; a += __shfl_xor(a, 1); a += __shfl_xor(a, 2); acc0[dd] = SPLIT ? a : a * inv0;
        float c2 = acc1[dd]; c2 += __shfl_xor(c2, 1); c2 += __shfl_xor(c2, 2); acc1[dd] = SPLIT ? c2 : c2 * inv1;
    }

    float* obase = SPLIT ? (outp + (size_t)split * NELEM) : outp;
    // static-index writes: 4-way branch on sub (keeps register arrays out of scratch)
    #define WRITE_SLICE(ro, a_, off) { \
        float4 o1 = make_float4(a_[(off)+0],a_[(off)+1],a_[(off)+2],a_[(off)+3]); \
        float4 o2 = make_float4(a_[(off)+4],a_[(off)+5],a_[(off)+6],a_[(off)+7]); \
        *(float4*)&obase[(rowbase + (ro))*C_ + coloff + (off)]     = o1; \
        *(float4*)&obase[(rowbase + (ro))*C_ + coloff + (off) + 4] = o2; }
    if      (sub == 0) { WRITE_SLICE(r0, acc0, 0)  WRITE_SLICE(r1, acc1, 0)  }
    else if (sub == 1) { WRITE_SLICE(r0, acc0, 8)  WRITE_SLICE(r1, acc1, 8)  }
    else if (sub == 2) { WRITE_SLICE(r0, acc0, 16) WRITE_SLICE(r1, acc1, 16) }
    else               { WRITE_SLICE(r0, acc0, 24) WRITE_SLICE(r1, acc1, 24) }
    #undef WRITE_SLICE

    if (SPLIT && sub == 0) {
        const size_t mlb = ((size_t)(split*B_ + b)*NH + hh)*S_;
        pm[mlb + r0] = m0; pl[mlb + r0] = l0;
        pm[mlb + r1] = m1; pl[mlb + r1] = l1;
    }
}

// ---------------- combine the two KV-split halves --------------------------------
// One thread per float4 of ctx; addresses are fully linear in gid.
__global__ __launch_bounds__(256) void combine_kernel(
        const float* __restrict__ pacc0, const float* __restrict__ pacc1,
        const float* __restrict__ pm, const float* __restrict__ pl,
        float* __restrict__ ctx)
{
    const int gid = blockIdx.x * 256 + threadIdx.x;   // 0 .. B_*S_*NH*8-1
    int rem = gid >> 3;                               // drop d4
    const int h = rem & 7; rem >>= 3;
    const int s = rem % S_;
    const int b = rem / S_;

    const size_t i0 = ((size_t)b*NH + h)*S_ + s;      // split 0
    const size_t i1 = i0 + (size_t)MLROWS;            // split 1
    const float m0 = pm[i0], l0 = pl[i0];
    const float m1 = pm[i1], l1 = pl[i1];
    const float M  = fmaxf(m0, m1);
    const float w0 = __expf(m0 - M);
    const float w1 = __expf(m1 - M);
    const float invL = 1.f / (l0*w0 + l1*w1);

    const size_t a = (size_t)gid * 4;                 // linear float4 address
    const float4 x0 = *(const float4*)&pacc0[a];
    const float4 x1 = *(const float4*)&pacc1[a];
    float4 o;
    o.x = (x0.x*w0 + x1.x*w1) * invL;
    o.y = (x0.y*w0 + x1.y*w1) * invL;
    o.z = (x0.z*w0 + x1.z*w1) * invL;
    o.w = (x0.w*w0 + x1.w*w1) * invL;
    *(float4*)&ctx[a] = o;
}

// ---------------- launch ---------------------------------------------------------
extern "C" void kernel_launch(void* const* d_in, const int* in_sizes, int n_in,
                              void* d_out, int out_size, void* d_ws, size_t ws_size,
                              hipStream_t stream)
{
    const float* x  = (const float*)d_in[0];
    const float* Wq = (const float*)d_in[1];
    const float* Wk = (const float*)d_in[2];
    const float* Wv = (const float*)d_in[3];
    const float* qb = (const float*)d_in[4];
    const float* vb = (const float*)d_in[5];
    const float* Wo = (const float*)d_in[6];
    const float* bo = (const float*)d_in[7];
    float* out = (float*)d_out;

    float* ws    = (float*)d_ws;
    float* q     = ws;
    float* k     = q + NELEM;
    float* v     = k + NELEM;
    float* ctx   = v + NELEM;
    float* pacc0 = ctx + NELEM;
    float* pacc1 = pacc0 + NELEM;
    float* pm    = pacc1 + NELEM;          // 2*MLROWS floats
    float* pl    = pm + 2*MLROWS;          // 2*MLROWS floats

    const size_t needed = ((size_t)6*NELEM + 4*(size_t)MLROWS) * sizeof(float);

    // q,k,v projections (+bias, q pre-scaled), 64x64 tiles
    qkv_kernel<<<dim3(96, 4, 3), 256, 0, stream>>>(x, Wq, Wk, Wv, qb, vb, q, k, v);
    // RoPE in place on q and k
    rope_kernel<<<6144, 256, 0, stream>>>(q, k);

    if (ws_size >= needed) {
        // split-KV flash attention: 1536 blocks -> 6 resident/CU -> 3 waves/SIMD
        attn_kernel<true><<<dim3(S_/64, NH, B_*2), 128, 0, stream>>>(q, k, v, pacc0, pm, pl);
        combine_kernel<<<(B_*S_*NH*8)/256, 256, 0, stream>>>(pacc0, pacc1, pm, pl, ctx);
    } else {
        // fallback: single-pass (768 blocks)
        attn_kernel<false><<<dim3(S_/64, NH, B_), 128, 0, stream>>>(q, k, v, ctx, nullptr, nullptr);
    }

    // output projection
    out_gemm_kernel<<<dim3(96, 4, 1), 256, 0, stream>>>(ctx, Wo, bo, out);
}

// Round 4
// 624.301 us; speedup vs baseline: 1.3702x; 1.3702x over previous
//
#include <hip/hip_runtime.h>
#include <math.h>

#define B_   2
#define S_   3072
#define C_   256
#define NH   8
#define HD   32
#define HALF 16
#define NELEM (B_*S_*C_)   // 1,572,864
#define MLROWS (B_*NH*S_)  // 49,152 rows per split

__device__ __forceinline__ float dot4(float4 a, float4 b) {
    return a.x*b.x + a.y*b.y + a.z*b.z + a.w*b.w;
}

// ---------------- GEMM: out[M x 256] = (A[M x 256] @ W[256 x 256]^T (+bias))*scl ---
// 64x64 tile, 256 threads, 4x4 microtile, K staged in 32-wide chunks.
__device__ __forceinline__ void gemm_nt_body(const float* __restrict__ A,
                                             const float* __restrict__ W,
                                             const float* __restrict__ bias,
                                             float* __restrict__ out,
                                             float scl)
{
    __shared__ float As[64][36];   // +4 pad keeps float4 alignment, breaks some conflicts
    __shared__ float Ws[64][36];
    const int tid  = threadIdx.x;
    const int tx4  = (tid & 15) * 4;   // col group
    const int ty4  = (tid >> 4) * 4;   // row group
    const int row0 = blockIdx.x * 64;
    const int col0 = blockIdx.y * 64;

    float acc[4][4] = {};

    for (int kc = 0; kc < C_; kc += 32) {
        __syncthreads();
        #pragma unroll
        for (int l = tid; l < 512; l += 256) {
            const int r  = l >> 3;
            const int k4 = (l & 7) * 4;
            *(float4*)&As[r][k4] = *(const float4*)&A[(size_t)(row0 + r)*C_ + kc + k4];
            *(float4*)&Ws[r][k4] = *(const float4*)&W[(size_t)(col0 + r)*C_ + kc + k4];
        }
        __syncthreads();
        #pragma unroll
        for (int k4 = 0; k4 < 32; k4 += 4) {
            float4 a0 = *(const float4*)&As[ty4+0][k4];
            float4 a1 = *(const float4*)&As[ty4+1][k4];
            float4 a2 = *(const float4*)&As[ty4+2][k4];
            float4 a3 = *(const float4*)&As[ty4+3][k4];
            float4 w0 = *(const float4*)&Ws[tx4+0][k4];
            float4 w1 = *(const float4*)&Ws[tx4+1][k4];
            float4 w2 = *(const float4*)&Ws[tx4+2][k4];
            float4 w3 = *(const float4*)&Ws[tx4+3][k4];
            acc[0][0] += dot4(a0,w0); acc[0][1] += dot4(a0,w1);
            acc[0][2] += dot4(a0,w2); acc[0][3] += dot4(a0,w3);
            acc[1][0] += dot4(a1,w0); acc[1][1] += dot4(a1,w1);
            acc[1][2] += dot4(a1,w2); acc[1][3] += dot4(a1,w3);
            acc[2][0] += dot4(a2,w0); acc[2][1] += dot4(a2,w1);
            acc[2][2] += dot4(a2,w2); acc[2][3] += dot4(a2,w3);
            acc[3][0] += dot4(a3,w0); acc[3][1] += dot4(a3,w1);
            acc[3][2] += dot4(a3,w2); acc[3][3] += dot4(a3,w3);
        }
    }

    float4 bv = make_float4(0.f, 0.f, 0.f, 0.f);
    if (bias) bv = *(const float4*)&bias[col0 + tx4];
    #pragma unroll
    for (int rr = 0; rr < 4; ++rr) {
        float4 o = make_float4((acc[rr][0] + bv.x)*scl, (acc[rr][1] + bv.y)*scl,
                               (acc[rr][2] + bv.z)*scl, (acc[rr][3] + bv.w)*scl);
        *(float4*)&out[(size_t)(row0 + ty4 + rr)*C_ + col0 + tx4] = o;
    }
}

__global__ __launch_bounds__(256) void qkv_kernel(
        const float* __restrict__ x,
        const float* __restrict__ Wq, const float* __restrict__ Wk, const float* __restrict__ Wv,
        const float* __restrict__ qb, const float* __restrict__ vb,
        float* __restrict__ q, float* __restrict__ k, float* __restrict__ v)
{
    // scale 1/sqrt(32) folded into q projection (RoPE rotation commutes with scalar)
    if      (blockIdx.z == 0) gemm_nt_body(x, Wq, qb,      q, 0.17677669529663687f);
    else if (blockIdx.z == 1) gemm_nt_body(x, Wk, nullptr, k, 1.0f);
    else                      gemm_nt_body(x, Wv, vb,      v, 1.0f);
}

__global__ __launch_bounds__(256) void out_gemm_kernel(
        const float* __restrict__ ctx, const float* __restrict__ Wo,
        const float* __restrict__ bo, float* __restrict__ out)
{
    gemm_nt_body(ctx, Wo, bo, out, 1.0f);
}

// ---------------- RoPE (in place on q and k), phase in double --------------------
__global__ __launch_bounds__(256) void rope_kernel(float* __restrict__ q, float* __restrict__ k)
{
    const int idx = blockIdx.x * 256 + threadIdx.x;   // grid sized exactly
    const int per_tensor = B_ * S_ * NH * HALF;       // 786432
    float* t = (idx < per_tensor) ? q : k;
    const int i   = (idx < per_tensor) ? idx : idx - per_tensor;
    const int j   = i & 15;
    const int hh  = (i >> 4) & 7;
    const int row = i >> 7;                            // 0 .. B_*S_-1
    const int s   = (row >= S_) ? (row - S_) : row;    // position within batch

    const double invf = exp(-log(10000.0) * (double)j * (1.0 / 16.0));
    // match reference: angle formed in fp32, then accurate sin/cos of that angle
    const float  angf = (float)((double)s * invf);
    double sn, cs;
    sincos((double)angf, &sn, &cs);
    const float c = (float)cs, sf = (float)sn;

    const size_t base = (size_t)row * C_ + hh * HD + j;
    const float t1 = t[base];
    const float t2 = t[base + HALF];
    t[base]        = t1 * c - t2 * sf;
    t[base + HALF] = t2 * c + t1 * sf;
}

// ---------------- softmax helpers: tree reductions (short dep chains) -------------
__device__ __forceinline__ float tree_max8(const float s[8]) {
    float t0 = fmaxf(s[0], s[4]), t1 = fmaxf(s[1], s[5]);
    float t2 = fmaxf(s[2], s[6]), t3 = fmaxf(s[3], s[7]);
    return fmaxf(fmaxf(t0, t2), fmaxf(t1, t3));
}
__device__ __forceinline__ float tree_sum8(const float s[8]) {
    float t0 = s[0] + s[4], t1 = s[1] + s[5];
    float t2 = s[2] + s[6], t3 = s[3] + s[7];
    return (t0 + t2) + (t1 + t3);
}

// ---------------- Flash attention, fp32, split-KV --------------------------------
// grid (S_/64, NH, B_*NSPLIT), 128 threads (2 waves). Thread t: rows
// {qb+(t>>2), qb+(t>>2)+32}, col sub-group sub = t&3 handles cols c = sub + 4*i.
// KVBLK=32, LDS 18 KB (double-buffered K+V) -> 8 blocks/CU LDS cap.
// SPLIT: 1536 blocks = 6 resident blocks/CU = 12 waves/CU = 3 waves/SIMD.
// NO min-waves clause: R3's __launch_bounds__(128,3) forced VGPR 84 and spilled
// both acc arrays (WRITE_SIZE 6 MB -> 2.2 GB). At the natural ~144 VGPR,
// floor(512/144) = 3 waves/SIMD already fits without spilling.
template<bool SPLIT>
__global__ __launch_bounds__(128) void attn_kernel(
        const float* __restrict__ q, const float* __restrict__ k,
        const float* __restrict__ v, float* __restrict__ outp,
        float* __restrict__ pm, float* __restrict__ pl)
{
    __shared__ float Ks[2][32][36];
    __shared__ float Vs[2][32][36];

    const int tid = threadIdx.x;
    const int sub = tid & 3;
    const int rr  = tid >> 2;                 // 0..31
    const int qb  = blockIdx.x * 64;
    const int hh  = blockIdx.y;
    const int split = SPLIT ? (blockIdx.z & 1) : 0;
    const int b     = SPLIT ? (blockIdx.z >> 1) : blockIdx.z;
    const int kt0   = split * (S_/2);
    const int NT    = SPLIT ? (S_/2)/32 : S_/32;   // 48 or 96 tiles

    const size_t rowbase = (size_t)b * S_;
    const int coloff = hh * HD;

    // staging: thread loads rows sr+{0,16}, cols [sk, sk+4) of the 32x32 tile
    const int sr = tid >> 3;                  // 0..15
    const int sk = (tid & 7) * 4;             // 0,4,...,28
    const float* kptr = &k[(rowbase + kt0)*C_ + coloff + sk];
    const float* vptr = &v[(rowbase + kt0)*C_ + coloff + sk];

    const int r0 = qb + rr, r1 = qb + rr + 32;

    float qreg0[32], qreg1[32];               // scale already folded into q
    #pragma unroll
    for (int k4 = 0; k4 < 32; k4 += 4) {
        float4 t0 = *(const float4*)&q[(rowbase + r0)*C_ + coloff + k4];
        float4 t1 = *(const float4*)&q[(rowbase + r1)*C_ + coloff + k4];
        qreg0[k4+0]=t0.x; qreg0[k4+1]=t0.y; qreg0[k4+2]=t0.z; qreg0[k4+3]=t0.w;
        qreg1[k4+0]=t1.x; qreg1[k4+1]=t1.y; qreg1[k4+2]=t1.z; qreg1[k4+3]=t1.w;
    }

    float4 kr0, kr1, vr0, vr1;

#define LOAD_TILE(t_) { \
        const size_t o = (size_t)((t_)*32 + sr) * C_; \
        kr0 = *(const float4*)&kptr[o        ]; \
        kr1 = *(const float4*)&kptr[o + 16*C_]; \
        vr0 = *(const float4*)&vptr[o        ]; \
        vr1 = *(const float4*)&vptr[o + 16*C_]; }

#define WRITE_TILE(bufi) { \
        *(float4*)&Ks[bufi][sr   ][sk] = kr0; \
        *(float4*)&Ks[bufi][sr+16][sk] = kr1; \
        *(float4*)&Vs[bufi][sr   ][sk] = vr0; \
        *(float4*)&Vs[bufi][sr+16][sk] = vr1; }

    float m0 = -1e30f, m1 = -1e30f, l0 = 0.f, l1 = 0.f;
    float acc0[32] = {}, acc1[32] = {};

    // prologue: tile 0 into buf0, tile 1 into regs
    LOAD_TILE(0);
    WRITE_TILE(0);
    LOAD_TILE(1);
    __syncthreads();

    for (int t = 0; t < NT; ++t) {
        const int cur = t & 1;
        const int nxt = cur ^ 1;
        if (t + 1 < NT) {
            WRITE_TILE(nxt);                  // tile t+1 regs -> other buffer
            if (t + 2 < NT) LOAD_TILE(t + 2); // refill regs; hides under compute
        }

        const float (*Kc)[36] = Ks[cur];
        const float (*Vc)[36] = Vs[cur];

        __builtin_amdgcn_s_setprio(1);
        // ---- scores for 8 cols x 2 rows (Ks read shared across both rows)
        float sc0[8], sc1[8];
        #pragma unroll
        for (int i = 0; i < 8; ++i) {
            const int c = sub + 4*i;           // 4 distinct rows/instr -> conflict-free
            float d0 = 0.f, d1 = 0.f;
            #pragma unroll
            for (int k4 = 0; k4 < 32; k4 += 4) {
                float4 kk = *(const float4*)&Kc[c][k4];
                d0 += qreg0[k4+0]*kk.x + qreg0[k4+1]*kk.y + qreg0[k4+2]*kk.z + qreg0[k4+3]*kk.w;
                d1 += qreg1[k4+0]*kk.x + qreg1[k4+1]*kk.y + qreg1[k4+2]*kk.z + qreg1[k4+3]*kk.w;
            }
            sc0[i] = d0; sc1[i] = d1;
        }

        // ---- online softmax bookkeeping, both rows (tree reductions)
        {
            float tm0 = tree_max8(sc0);
            float tm1 = tree_max8(sc1);
            tm0 = fmaxf(tm0, __shfl_xor(tm0, 1));
            tm0 = fmaxf(tm0, __shfl_xor(tm0, 2));
            tm1 = fmaxf(tm1, __shfl_xor(tm1, 1));
            tm1 = fmaxf(tm1, __shfl_xor(tm1, 2));
            const float mnew0 = fmaxf(m0, tm0);
            const float mnew1 = fmaxf(m1, tm1);
            const float f0 = __expf(m0 - mnew0);
            const float f1 = __expf(m1 - mnew1);
            m0 = mnew0; m1 = mnew1; l0 *= f0; l1 *= f1;
            #pragma unroll
            for (int dd = 0; dd < 32; ++dd) { acc0[dd] *= f0; acc1[dd] *= f1; }
            #pragma unroll
            for (int i = 0; i < 8; ++i) {
                sc0[i] = __expf(sc0[i] - mnew0);
                sc1[i] = __expf(sc1[i] - mnew1);
            }
            l0 += tree_sum8(sc0);
            l1 += tree_sum8(sc1);
        }

        // ---- PV, fused over both rows: each Vs float4 read feeds 8 FMAs
        #pragma unroll
        for (int i = 0; i < 8; ++i) {
            const int c = sub + 4*i;
            const float p0 = sc0[i];
            const float p1 = sc1[i];
            #pragma unroll
            for (int d4 = 0; d4 < 8; ++d4) {
                float4 vv = *(const float4*)&Vc[c][d4*4];
                acc0[d4*4+0] += p0*vv.x; acc0[d4*4+1] += p0*vv.y;
                acc0[d4*4+2] += p0*vv.z; acc0[d4*4+3] += p0*vv.w;
                acc1[d4*4+0] += p1*vv.x; acc1[d4*4+1] += p1*vv.y;
                acc1[d4*4+2] += p1*vv.z; acc1[d4*4+3] += p1*vv.w;
            }
        }
        __builtin_amdgcn_s_setprio(0);

        __syncthreads();                       // single barrier per tile
    }

#undef LOAD_TILE
#undef WRITE_TILE

    // ---- reduce across the 4-lane row group; normalize only if single-pass
    l0 += __shfl_xor(l0, 1); l0 += __shfl_xor(l0, 2);
    l1 += __shfl_xor(l1, 1); l1 += __shfl_xor(l1, 2);
    const float inv0 = SPLIT ? 1.f : 1.f / l0;
    const float inv1 = SPLIT ? 1.f : 1.f / l1;
    #pragma unroll
    for (int dd = 0; dd < 32; ++dd) {
        float a = acc0[dd]; a += __shfl_xor(a, 1); a += __shfl_xor(a, 2); acc0[dd] = SPLIT ? a : a * inv0;
        float c2 = acc1[dd]; c2 += __shfl_xor(c2, 1); c2 += __shfl_xor(c2, 2); acc1[dd] = SPLIT ? c2 : c2 * inv1;
    }

    float* obase = SPLIT ? (outp + (size_t)split * NELEM) : outp;
    // static-index writes: 4-way branch on sub (keeps register arrays out of scratch)
    #define WRITE_SLICE(ro, a_, off) { \
        float4 o1 = make_float4(a_[(off)+0],a_[(off)+1],a_[(off)+2],a_[(off)+3]); \
        float4 o2 = make_float4(a_[(off)+4],a_[(off)+5],a_[(off)+6],a_[(off)+7]); \
        *(float4*)&obase[(rowbase + (ro))*C_ + coloff + (off)]     = o1; \
        *(float4*)&obase[(rowbase + (ro))*C_ + coloff + (off) + 4] = o2; }
    if      (sub == 0) { WRITE_SLICE(r0, acc0, 0)  WRITE_SLICE(r1, acc1, 0)  }
    else if (sub == 1) { WRITE_SLICE(r0, acc0, 8)  WRITE_SLICE(r1, acc1, 8)  }
    else if (sub == 2) { WRITE_SLICE(r0, acc0, 16) WRITE_SLICE(r1, acc1, 16) }
    else               { WRITE_SLICE(r0, acc0, 24) WRITE_SLICE(r1, acc1, 24) }
    #undef WRITE_SLICE

    if (SPLIT && sub == 0) {
        const size_t mlb = ((size_t)(split*B_ + b)*NH + hh)*S_;
        pm[mlb + r0] = m0; pl[mlb + r0] = l0;
        pm[mlb + r1] = m1; pl[mlb + r1] = l1;
    }
}

// ---------------- combine the two KV-split halves --------------------------------
// One thread per float4 of ctx; addresses are fully linear in gid.
__global__ __launch_bounds__(256) void combine_kernel(
        const float* __restrict__ pacc0, const float* __restrict__ pacc1,
        const float* __restrict__ pm, const float* __restrict__ pl,
        float* __restrict__ ctx)
{
    const int gid = blockIdx.x * 256 + threadIdx.x;   // 0 .. B_*S_*NH*8-1
    int rem = gid >> 3;                               // drop d4
    const int h = rem & 7; rem >>= 3;
    const int s = rem % S_;
    const int b = rem / S_;

    const size_t i0 = ((size_t)b*NH + h)*S_ + s;      // split 0
    const size_t i1 = i0 + (size_t)MLROWS;            // split 1
    const float m0 = pm[i0], l0 = pl[i0];
    const float m1 = pm[i1], l1 = pl[i1];
    const float M  = fmaxf(m0, m1);
    const float w0 = __expf(m0 - M);
    const float w1 = __expf(m1 - M);
    const float invL = 1.f / (l0*w0 + l1*w1);

    const size_t a = (size_t)gid * 4;                 // linear float4 address
    const float4 x0 = *(const float4*)&pacc0[a];
    const float4 x1 = *(const float4*)&pacc1[a];
    float4 o;
    o.x = (x0.x*w0 + x1.x*w1) * invL;
    o.y = (x0.y*w0 + x1.y*w1) * invL;
    o.z = (x0.z*w0 + x1.z*w1) * invL;
    o.w = (x0.w*w0 + x1.w*w1) * invL;
    *(float4*)&ctx[a] = o;
}

// ---------------- launch ---------------------------------------------------------
extern "C" void kernel_launch(void* const* d_in, const int* in_sizes, int n_in,
                              void* d_out, int out_size, void* d_ws, size_t ws_size,
                              hipStream_t stream)
{
    const float* x  = (const float*)d_in[0];
    const float* Wq = (const float*)d_in[1];
    const float* Wk = (const float*)d_in[2];
    const float* Wv = (const float*)d_in[3];
    const float* qb = (const float*)d_in[4];
    const float* vb = (const float*)d_in[5];
    const float* Wo = (const float*)d_in[6];
    const float* bo = (const float*)d_in[7];
    float* out = (float*)d_out;

    float* ws    = (float*)d_ws;
    float* q     = ws;
    float* k     = q + NELEM;
    float* v     = k + NELEM;
    float* ctx   = v + NELEM;
    float* pacc0 = ctx + NELEM;
    float* pacc1 = pacc0 + NELEM;
    float* pm    = pacc1 + NELEM;          // 2*MLROWS floats
    float* pl    = pm + 2*MLROWS;          // 2*MLROWS floats

    const size_t needed = ((size_t)6*NELEM + 4*(size_t)MLROWS) * sizeof(float);

    // q,k,v projections (+bias, q pre-scaled), 64x64 tiles
    qkv_kernel<<<dim3(96, 4, 3), 256, 0, stream>>>(x, Wq, Wk, Wv, qb, vb, q, k, v);
    // RoPE in place on q and k
    rope_kernel<<<6144, 256, 0, stream>>>(q, k);

    if (ws_size >= needed) {
        // split-KV flash attention: 1536 blocks -> 6 resident/CU -> 3 waves/SIMD
        attn_kernel<true><<<dim3(S_/64, NH, B_*2), 128, 0, stream>>>(q, k, v, pacc0, pm, pl);
        combine_kernel<<<(B_*S_*NH*8)/256, 256, 0, stream>>>(pacc0, pacc1, pm, pl, ctx);
    } else {
        // fallback: single-pass (768 blocks)
        attn_kernel<false><<<dim3(S_/64, NH, B_), 128, 0, stream>>>(q, k, v, ctx, nullptr, nullptr);
    }

    // output projection
    out_gemm_kernel<<<dim3(96, 4, 1), 256, 0, stream>>>(ctx, Wo, bo, out);
}

// Round 5
// 585.701 us; speedup vs baseline: 1.4605x; 1.0659x over previous
//
#include <hip/hip_runtime.h>
#include <math.h>

#define B_   2
#define S_   3072
#define C_   256
#define NH   8
#define HD   32
#define HALF 16
#define NELEM (B_*S_*C_)   // 1,572,864
#define MLROWS (B_*NH*S_)  // 49,152 rows per split

__device__ __forceinline__ float dot4(float4 a, float4 b) {
    return a.x*b.x + a.y*b.y + a.z*b.z + a.w*b.w;
}

// direct global->LDS copy, 16B per lane; LDS dest is wave-uniform base + lane*16
__device__ __forceinline__ void gload_lds16(const float* g, float* l) {
    __builtin_amdgcn_global_load_lds(
        (const __attribute__((address_space(1))) unsigned int*)g,
        (__attribute__((address_space(3))) unsigned int*)l, 16, 0, 0);
}

// ---------------- GEMM: out[M x 256] = (A[M x 256] @ W[256 x 256]^T (+bias))*scl ---
// 64x64 tile, 256 threads, 4x4 microtile, K staged in 32-wide chunks.
__device__ __forceinline__ void gemm_nt_body(const float* __restrict__ A,
                                             const float* __restrict__ W,
                                             const float* __restrict__ bias,
                                             float* __restrict__ out,
                                             float scl)
{
    __shared__ float As[64][36];   // +4 pad keeps float4 alignment, breaks some conflicts
    __shared__ float Ws[64][36];
    const int tid  = threadIdx.x;
    const int tx4  = (tid & 15) * 4;   // col group
    const int ty4  = (tid >> 4) * 4;   // row group
    const int row0 = blockIdx.x * 64;
    const int col0 = blockIdx.y * 64;

    float acc[4][4] = {};

    for (int kc = 0; kc < C_; kc += 32) {
        __syncthreads();
        #pragma unroll
        for (int l = tid; l < 512; l += 256) {
            const int r  = l >> 3;
            const int k4 = (l & 7) * 4;
            *(float4*)&As[r][k4] = *(const float4*)&A[(size_t)(row0 + r)*C_ + kc + k4];
            *(float4*)&Ws[r][k4] = *(const float4*)&W[(size_t)(col0 + r)*C_ + kc + k4];
        }
        __syncthreads();
        #pragma unroll
        for (int k4 = 0; k4 < 32; k4 += 4) {
            float4 a0 = *(const float4*)&As[ty4+0][k4];
            float4 a1 = *(const float4*)&As[ty4+1][k4];
            float4 a2 = *(const float4*)&As[ty4+2][k4];
            float4 a3 = *(const float4*)&As[ty4+3][k4];
            float4 w0 = *(const float4*)&Ws[tx4+0][k4];
            float4 w1 = *(const float4*)&Ws[tx4+1][k4];
            float4 w2 = *(const float4*)&Ws[tx4+2][k4];
            float4 w3 = *(const float4*)&Ws[tx4+3][k4];
            acc[0][0] += dot4(a0,w0); acc[0][1] += dot4(a0,w1);
            acc[0][2] += dot4(a0,w2); acc[0][3] += dot4(a0,w3);
            acc[1][0] += dot4(a1,w0); acc[1][1] += dot4(a1,w1);
            acc[1][2] += dot4(a1,w2); acc[1][3] += dot4(a1,w3);
            acc[2][0] += dot4(a2,w0); acc[2][1] += dot4(a2,w1);
            acc[2][2] += dot4(a2,w2); acc[2][3] += dot4(a2,w3);
            acc[3][0] += dot4(a3,w0); acc[3][1] += dot4(a3,w1);
            acc[3][2] += dot4(a3,w2); acc[3][3] += dot4(a3,w3);
        }
    }

    float4 bv = make_float4(0.f, 0.f, 0.f, 0.f);
    if (bias) bv = *(const float4*)&bias[col0 + tx4];
    #pragma unroll
    for (int rr = 0; rr < 4; ++rr) {
        float4 o = make_float4((acc[rr][0] + bv.x)*scl, (acc[rr][1] + bv.y)*scl,
                               (acc[rr][2] + bv.z)*scl, (acc[rr][3] + bv.w)*scl);
        *(float4*)&out[(size_t)(row0 + ty4 + rr)*C_ + col0 + tx4] = o;
    }
}

__global__ __launch_bounds__(256) void qkv_kernel(
        const float* __restrict__ x,
        const float* __restrict__ Wq, const float* __restrict__ Wk, const float* __restrict__ Wv,
        const float* __restrict__ qb, const float* __restrict__ vb,
        float* __restrict__ q, float* __restrict__ k, float* __restrict__ v)
{
    // scale 1/sqrt(32) folded into q projection (RoPE rotation commutes with scalar)
    if      (blockIdx.z == 0) gemm_nt_body(x, Wq, qb,      q, 0.17677669529663687f);
    else if (blockIdx.z == 1) gemm_nt_body(x, Wk, nullptr, k, 1.0f);
    else                      gemm_nt_body(x, Wv, vb,      v, 1.0f);
}

__global__ __launch_bounds__(256) void out_gemm_kernel(
        const float* __restrict__ ctx, const float* __restrict__ Wo,
        const float* __restrict__ bo, float* __restrict__ out)
{
    gemm_nt_body(ctx, Wo, bo, out, 1.0f);
}

// ---------------- RoPE (in place on q and k), phase in double --------------------
__global__ __launch_bounds__(256) void rope_kernel(float* __restrict__ q, float* __restrict__ k)
{
    const int idx = blockIdx.x * 256 + threadIdx.x;   // grid sized exactly
    const int per_tensor = B_ * S_ * NH * HALF;       // 786432
    float* t = (idx < per_tensor) ? q : k;
    const int i   = (idx < per_tensor) ? idx : idx - per_tensor;
    const int j   = i & 15;
    const int hh  = (i >> 4) & 7;
    const int row = i >> 7;                            // 0 .. B_*S_-1
    const int s   = (row >= S_) ? (row - S_) : row;    // position within batch

    const double invf = exp(-log(10000.0) * (double)j * (1.0 / 16.0));
    // match reference: angle formed in fp32, then accurate sin/cos of that angle
    const float  angf = (float)((double)s * invf);
    double sn, cs;
    sincos((double)angf, &sn, &cs);
    const float c = (float)cs, sf = (float)sn;

    const size_t base = (size_t)row * C_ + hh * HD + j;
    const float t1 = t[base];
    const float t2 = t[base + HALF];
    t[base]        = t1 * c - t2 * sf;
    t[base + HALF] = t2 * c + t1 * sf;
}

// ---------------- softmax helpers: tree reductions (short dep chains) -------------
__device__ __forceinline__ float tree_max8(const float s[8]) {
    float t0 = fmaxf(s[0], s[4]), t1 = fmaxf(s[1], s[5]);
    float t2 = fmaxf(s[2], s[6]), t3 = fmaxf(s[3], s[7]);
    return fmaxf(fmaxf(t0, t2), fmaxf(t1, t3));
}
__device__ __forceinline__ float tree_sum8(const float s[8]) {
    float t0 = s[0] + s[4], t1 = s[1] + s[5];
    float t2 = s[2] + s[6], t3 = s[3] + s[7];
    return (t0 + t2) + (t1 + t3);
}

// ---------------- Flash attention, fp32, split-KV --------------------------------
// grid (S_/64, NH, B_*NSPLIT), 128 threads (2 waves). Thread t: rows
// {qb+(t>>2), qb+(t>>2)+32}, col sub-group sub = t&3 handles cols c = sub + 4*i.
//
// Staging: global_load_lds (16B/lane), wave 0 -> K, wave 1 -> V. LDS is written
// LINEARLY (no padding possible), so bank conflicts are broken by an XOR swizzle
// applied on the GLOBAL source address: LDS[row][p] = G[row][p ^ (row&7)] at
// float4 granularity. Reads use offset ((c4 ^ (row&7))<<2); the 4 lanes of a
// sub-group (rows sub+4i) then hit 4 distinct bank quads -> conflict-free.
//
// __launch_bounds__(128,2): VGPR cap 128 (hardware occupancy step at 128, m69)
// -> 16 waves/CU -> all 6 blocks/CU of the 1536-block grid co-resident.
template<bool SPLIT>
__global__ __launch_bounds__(128, 2) void attn_kernel(
        const float* __restrict__ q, const float* __restrict__ k,
        const float* __restrict__ v, float* __restrict__ outp,
        float* __restrict__ pm, float* __restrict__ pl)
{
    __shared__ float SM[2][2][32*32];   // [buf][0=K,1=V][row*32 + swizzled col] 16 KB

    const int tid  = threadIdx.x;
    const int lane = tid & 63;
    const int wid  = tid >> 6;
    const int sub  = tid & 3;
    const int rr   = tid >> 2;                // 0..31
    const int qb   = blockIdx.x * 64;
    const int hh   = blockIdx.y;
    const int split = SPLIT ? (blockIdx.z & 1) : 0;
    const int b     = SPLIT ? (blockIdx.z >> 1) : blockIdx.z;
    const int kt0   = split * (S_/2);
    const int NT    = SPLIT ? (S_/2)/32 : S_/32;   // 48 or 96 tiles

    const size_t rowbase = (size_t)b * S_;
    const int coloff = hh * HD;

    // per-lane swizzled global source: lane covers row (8j + lane>>3),
    // physical col4 (lane&7); source logical col4 = (lane&7) ^ (lane>>3)
    const int srow = lane >> 3;                   // 0..7
    const int scol = ((lane & 7) ^ srow) << 2;    // swizzled float col
    const float* gstage = (wid == 0)
        ? &k[(rowbase + kt0 + srow)*C_ + coloff + scol]
        : &v[(rowbase + kt0 + srow)*C_ + coloff + scol];

    const int r0 = qb + rr, r1 = qb + rr + 32;

    float qreg0[32], qreg1[32];               // scale already folded into q
    #pragma unroll
    for (int k4 = 0; k4 < 32; k4 += 4) {
        float4 t0 = *(const float4*)&q[(rowbase + r0)*C_ + coloff + k4];
        float4 t1 = *(const float4*)&q[(rowbase + r1)*C_ + coloff + k4];
        qreg0[k4+0]=t0.x; qreg0[k4+1]=t0.y; qreg0[k4+2]=t0.z; qreg0[k4+3]=t0.w;
        qreg1[k4+0]=t1.x; qreg1[k4+1]=t1.y; qreg1[k4+2]=t1.z; qreg1[k4+3]=t1.w;
    }

    // each wave issues 4 direct-to-LDS loads per tile (8 rows x 128B each)
#define ISSUE_TILE(t_, bufi) { \
        const float* gs = gstage + (size_t)(t_)*(32*C_); \
        float* lb = &SM[bufi][wid][0]; \
        gload_lds16(gs         , lb      ); \
        gload_lds16(gs +  8*C_ , lb + 256); \
        gload_lds16(gs + 16*C_ , lb + 512); \
        gload_lds16(gs + 24*C_ , lb + 768); }

    float m0 = -1e30f, m1 = -1e30f, l0 = 0.f, l1 = 0.f;
    float acc0[32] = {}, acc1[32] = {};

    // prologue: tile 0 into buf0 (syncthreads drains vmcnt+lgkmcnt)
    ISSUE_TILE(0, 0);
    __syncthreads();

    for (int t = 0; t < NT; ++t) {
        const int cur = t & 1;
        if (t + 1 < NT) ISSUE_TILE(t + 1, cur ^ 1);   // async; lands before next barrier

        const float* Kc = &SM[cur][0][0];
        const float* Vc = &SM[cur][1][0];

        __builtin_amdgcn_s_setprio(1);
        // ---- scores for 8 cols x 2 rows (swizzled reads, conflict-free)
        float sc0[8], sc1[8];
        #pragma unroll
        for (int i = 0; i < 8; ++i) {
            const int c  = sub + 4*i;
            const int cb = c & 7;
            const float* kr = Kc + c*32;
            float d0 = 0.f, d1 = 0.f;
            #pragma unroll
            for (int c4 = 0; c4 < 8; ++c4) {
                float4 kk = *(const float4*)&kr[(c4 ^ cb) << 2];
                d0 += qreg0[c4*4+0]*kk.x + qreg0[c4*4+1]*kk.y + qreg0[c4*4+2]*kk.z + qreg0[c4*4+3]*kk.w;
                d1 += qreg1[c4*4+0]*kk.x + qreg1[c4*4+1]*kk.y + qreg1[c4*4+2]*kk.z + qreg1[c4*4+3]*kk.w;
            }
            sc0[i] = d0; sc1[i] = d1;
        }

        // ---- online softmax bookkeeping, both rows (tree reductions)
        {
            float tm0 = tree_max8(sc0);
            float tm1 = tree_max8(sc1);
            tm0 = fmaxf(tm0, __shfl_xor(tm0, 1));
            tm0 = fmaxf(tm0, __shfl_xor(tm0, 2));
            tm1 = fmaxf(tm1, __shfl_xor(tm1, 1));
            tm1 = fmaxf(tm1, __shfl_xor(tm1, 2));
            const float mnew0 = fmaxf(m0, tm0);
            const float mnew1 = fmaxf(m1, tm1);
            const float f0 = __expf(m0 - mnew0);
            const float f1 = __expf(m1 - mnew1);
            m0 = mnew0; m1 = mnew1; l0 *= f0; l1 *= f1;
            #pragma unroll
            for (int dd = 0; dd < 32; ++dd) { acc0[dd] *= f0; acc1[dd] *= f1; }
            #pragma unroll
            for (int i = 0; i < 8; ++i) {
                sc0[i] = __expf(sc0[i] - mnew0);
                sc1[i] = __expf(sc1[i] - mnew1);
            }
            l0 += tree_sum8(sc0);
            l1 += tree_sum8(sc1);
        }

        // ---- PV, fused over both rows: each Vs float4 read feeds 8 FMAs
        #pragma unroll
        for (int i = 0; i < 8; ++i) {
            const int c  = sub + 4*i;
            const int cb = c & 7;
            const float* vrow = Vc + c*32;
            const float p0 = sc0[i];
            const float p1 = sc1[i];
            #pragma unroll
            for (int d4 = 0; d4 < 8; ++d4) {
                float4 vv = *(const float4*)&vrow[(d4 ^ cb) << 2];
                acc0[d4*4+0] += p0*vv.x; acc0[d4*4+1] += p0*vv.y;
                acc0[d4*4+2] += p0*vv.z; acc0[d4*4+3] += p0*vv.w;
                acc1[d4*4+0] += p1*vv.x; acc1[d4*4+1] += p1*vv.y;
                acc1[d4*4+2] += p1*vv.z; acc1[d4*4+3] += p1*vv.w;
            }
        }
        __builtin_amdgcn_s_setprio(0);

        __syncthreads();   // single barrier/tile; drains vmcnt (loads) + lgkmcnt (reads)
    }

#undef ISSUE_TILE

    // ---- reduce across the 4-lane row group; normalize only if single-pass
    l0 += __shfl_xor(l0, 1); l0 += __shfl_xor(l0, 2);
    l1 += __shfl_xor(l1, 1); l1 += __shfl_xor(l1, 2);
    const float inv0 = SPLIT ? 1.f : 1.f / l0;
    const float inv1 = SPLIT ? 1.f : 1.f / l1;
    #pragma unroll
    for (int dd = 0; dd < 32; ++dd) {
        float a = acc0[dd]; a += __shfl_xor(a, 1); a += __shfl_xor(a, 2); acc0[dd] = SPLIT ? a : a * inv0;
        float c2 = acc1[dd]; c2 += __shfl_xor(c2, 1); c2 += __shfl_xor(c2, 2); acc1[dd] = SPLIT ? c2 : c2 * inv1;
    }

    float* obase = SPLIT ? (outp + (size_t)split * NELEM) : outp;
    // static-index writes: 4-way branch on sub (keeps register arrays out of scratch)
    #define WRITE_SLICE(ro, a_, off) { \
        float4 o1 = make_float4(a_[(off)+0],a_[(off)+1],a_[(off)+2],a_[(off)+3]); \
        float4 o2 = make_float4(a_[(off)+4],a_[(off)+5],a_[(off)+6],a_[(off)+7]); \
        *(float4*)&obase[(rowbase + (ro))*C_ + coloff + (off)]     = o1; \
        *(float4*)&obase[(rowbase + (ro))*C_ + coloff + (off) + 4] = o2; }
    if      (sub == 0) { WRITE_SLICE(r0, acc0, 0)  WRITE_SLICE(r1, acc1, 0)  }
    else if (sub == 1) { WRITE_SLICE(r0, acc0, 8)  WRITE_SLICE(r1, acc1, 8)  }
    else if (sub == 2) { WRITE_SLICE(r0, acc0, 16) WRITE_SLICE(r1, acc1, 16) }
    else               { WRITE_SLICE(r0, acc0, 24) WRITE_SLICE(r1, acc1, 24) }
    #undef WRITE_SLICE

    if (SPLIT && sub == 0) {
        const size_t mlb = ((size_t)(split*B_ + b)*NH + hh)*S_;
        pm[mlb + r0] = m0; pl[mlb + r0] = l0;
        pm[mlb + r1] = m1; pl[mlb + r1] = l1;
    }
}

// ---------------- combine the two KV-split halves --------------------------------
// One thread per float4 of ctx; addresses are fully linear in gid.
__global__ __launch_bounds__(256) void combine_kernel(
        const float* __restrict__ pacc0, const float* __restrict__ pacc1,
        const float* __restrict__ pm, const float* __restrict__ pl,
        float* __restrict__ ctx)
{
    const int gid = blockIdx.x * 256 + threadIdx.x;   // 0 .. B_*S_*NH*8-1
    int rem = gid >> 3;                               // drop d4
    const int h = rem & 7; rem >>= 3;
    const int s = rem % S_;
    const int b = rem / S_;

    const size_t i0 = ((size_t)b*NH + h)*S_ + s;      // split 0
    const size_t i1 = i0 + (size_t)MLROWS;            // split 1
    const float m0 = pm[i0], l0 = pl[i0];
    const float m1 = pm[i1], l1 = pl[i1];
    const float M  = fmaxf(m0, m1);
    const float w0 = __expf(m0 - M);
    const float w1 = __expf(m1 - M);
    const float invL = 1.f / (l0*w0 + l1*w1);

    const size_t a = (size_t)gid * 4;                 // linear float4 address
    const float4 x0 = *(const float4*)&pacc0[a];
    const float4 x1 = *(const float4*)&pacc1[a];
    float4 o;
    o.x = (x0.x*w0 + x1.x*w1) * invL;
    o.y = (x0.y*w0 + x1.y*w1) * invL;
    o.z = (x0.z*w0 + x1.z*w1) * invL;
    o.w = (x0.w*w0 + x1.w*w1) * invL;
    *(float4*)&ctx[a] = o;
}

// ---------------- launch ---------------------------------------------------------
extern "C" void kernel_launch(void* const* d_in, const int* in_sizes, int n_in,
                              void* d_out, int out_size, void* d_ws, size_t ws_size,
                              hipStream_t stream)
{
    const float* x  = (const float*)d_in[0];
    const float* Wq = (const float*)d_in[1];
    const float* Wk = (const float*)d_in[2];
    const float* Wv = (const float*)d_in[3];
    const float* qb = (const float*)d_in[4];
    const float* vb = (const float*)d_in[5];
    const float* Wo = (const float*)d_in[6];
    const float* bo = (const float*)d_in[7];
    float* out = (float*)d_out;

    float* ws    = (float*)d_ws;
    float* q     = ws;
    float* k     = q + NELEM;
    float* v     = k + NELEM;
    float* ctx   = v + NELEM;
    float* pacc0 = ctx + NELEM;
    float* pacc1 = pacc0 + NELEM;
    float* pm    = pacc1 + NELEM;          // 2*MLROWS floats
    float* pl    = pm + 2*MLROWS;          // 2*MLROWS floats

    const size_t needed = ((size_t)6*NELEM + 4*(size_t)MLROWS) * sizeof(float);

    // q,k,v projections (+bias, q pre-scaled), 64x64 tiles
    qkv_kernel<<<dim3(96, 4, 3), 256, 0, stream>>>(x, Wq, Wk, Wv, qb, vb, q, k, v);
    // RoPE in place on q and k
    rope_kernel<<<6144, 256, 0, stream>>>(q, k);

    if (ws_size >= needed) {
        // split-KV flash attention: 1536 blocks -> 6 resident/CU -> 3 waves/SIMD
        attn_kernel<true><<<dim3(S_/64, NH, B_*2), 128, 0, stream>>>(q, k, v, pacc0, pm, pl);
        combine_kernel<<<(B_*S_*NH*8)/256, 256, 0, stream>>>(pacc0, pacc1, pm, pl, ctx);
    } else {
        // fallback: single-pass (768 blocks)
        attn_kernel<false><<<dim3(S_/64, NH, B_), 128, 0, stream>>>(q, k, v, ctx, nullptr, nullptr);
    }

    // output projection
    out_gemm_kernel<<<dim3(96, 4, 1), 256, 0, stream>>>(ctx, Wo, bo, out);
}